// Round 17
// baseline (294.875 us; speedup 1.0000x reference)
//
#include <hip/hip_runtime.h>
#include <hip/hip_bf16.h>

#define B_  16
#define S_  2048
#define F_  800
#define E_  200
#define EP  224          // padded E (multiple of 32)
#define KP  832          // padded K (26 * 32)
#define KSP 256          // kbuf row pitch in shorts (32 x 16B slots, pow2 for swizzle)
#define M_  (B_ * S_)    // 32768

typedef __attribute__((ext_vector_type(8))) short short8;
typedef __attribute__((ext_vector_type(4))) float f32x4;

// scale = 1/sqrt(960); folded with log2(e) into Q so softmax runs in exp2 domain
#define QSCL (0.03227486121839514f * 1.4426950408889634f)

__device__ __forceinline__ unsigned short f2bf(float f) {
    __hip_bfloat16 h = __float2bfloat16(f);
    return *reinterpret_cast<unsigned short*>(&h);
}

__device__ __forceinline__ float exp2_fast(float x) {
    float r;
    asm("v_exp_f32 %0, %1" : "=v"(r) : "v"(x));
    return r;
}

__device__ __forceinline__ float rcp_fast(float x) {
    float r;
    asm("v_rcp_f32 %0, %1" : "=v"(r) : "v"(x));
    return r;
}

// tanh-form GELU (max |err| vs exact ~5e-4, below bf16 noise here)
__device__ __forceinline__ float gelu_fast(float x) {
    const float i = x + 0.044715f * x * x * x;
    const float z = 2.302265314f * i;              // 2*0.79788456*log2(e) * i
    return x * rcp_fast(1.0f + exp2_fast(-z));
}

__device__ __forceinline__ void gload_lds16(const void* g, void* l) {
    __builtin_amdgcn_global_load_lds(
        (const __attribute__((address_space(1))) unsigned int*)g,
        (__attribute__((address_space(3))) unsigned int*)l, 16, 0, 0);
}

// ---------------- prep: X fp32 -> bf16 padded [M][KP] ----------------
__global__ __launch_bounds__(256)
void prep_x(const float* __restrict__ x, unsigned short* __restrict__ xb) {
    const int id = blockIdx.x * 256 + threadIdx.x;
    const int r  = id / (KP / 8);
    const int c8 = id % (KP / 8);
    ushort4 lo = {0, 0, 0, 0}, hi = {0, 0, 0, 0};
    if (c8 < F_ / 8) {
        const float4 a = *reinterpret_cast<const float4*>(x + (size_t)r * F_ + c8 * 8);
        const float4 b = *reinterpret_cast<const float4*>(x + (size_t)r * F_ + c8 * 8 + 4);
        lo.x = f2bf(a.x); lo.y = f2bf(a.y); lo.z = f2bf(a.z); lo.w = f2bf(a.w);
        hi.x = f2bf(b.x); hi.y = f2bf(b.y); hi.z = f2bf(b.z); hi.w = f2bf(b.w);
    }
    unsigned short* dst = xb + (size_t)r * KP + c8 * 8;
    *reinterpret_cast<ushort4*>(dst) = lo;
    *reinterpret_cast<ushort4*>(dst + 4) = hi;
}

// ---------------- prep: W^T bf16 padded wt[3][EP][KP] ----------------
__global__ __launch_bounds__(256)
void prep_w(const float* __restrict__ Wq, const float* __restrict__ Wk,
            const float* __restrict__ Wv, unsigned short* __restrict__ wt) {
    const int id = blockIdx.x * 256 + threadIdx.x;
    const int sel = id / (EP * KP);
    const int rem = id % (EP * KP);
    const int e = rem / KP;
    const int k = rem % KP;
    const float* W = (sel == 0) ? Wq : ((sel == 1) ? Wk : Wv);
    float v = (e < E_ && k < F_) ? W[(size_t)k * E_ + e] : 0.0f;
    wt[id] = f2bf(v);
}

// ---------------- Stage 1 GEMM: Q/K/V = gelu(Xb @ W) ----------------
// (unchanged from the round-13/15 passing source)
#define STAGE(XB, WB, KK) do {                                                   \
    const int k0s = (KK) * 32;                                                   \
    _Pragma("unroll")                                                            \
    for (int i = 0; i < 2; ++i) {                                                \
        const int j = w * 2 + i;                                                 \
        const int row = 16 * j + rS;                                             \
        gload_lds16(xb + (size_t)(m0 + row) * KP + k0s + ((pS ^ (row & 3)) * 8), \
                    &XB[j * 512]);                                               \
    }                                                                            \
    _Pragma("unroll")                                                            \
    for (int i = 0; i < 4; ++i) {                                                \
        const int j = i * 4 + w;                                                 \
        if (j < 14) {                                                            \
            const int row = 16 * j + rS;                                         \
            gload_lds16(wsel + (size_t)row * KP + k0s + ((pS ^ (row & 3)) * 8),  \
                        &WB[j * 512]);                                           \
        }                                                                        \
    }                                                                            \
} while (0)

#define COMPUTE(XB, WB) do {                                                     \
    short8 afr[4];                                                               \
    _Pragma("unroll")                                                            \
    for (int rf = 0; rf < 4; ++rf) {                                             \
        const int row = wr * 64 + rf * 16 + ln15;                                \
        afr[rf] = *reinterpret_cast<const short8*>(                              \
            &XB[row * 32 + ((g ^ (row & 3)) * 8)]);                              \
    }                                                                            \
    _Pragma("unroll")                                                            \
    for (int cf = 0; cf < 7; ++cf) {                                             \
        const int row = wc * 112 + cf * 16 + ln15;                               \
        short8 bfr = *reinterpret_cast<const short8*>(                           \
            &WB[row * 32 + ((g ^ (row & 3)) * 8)]);                              \
        _Pragma("unroll")                                                        \
        for (int rf = 0; rf < 4; ++rf)                                           \
            acc[rf][cf] = __builtin_amdgcn_mfma_f32_16x16x32_bf16(               \
                afr[rf], bfr, acc[rf][cf], 0, 0, 0);                             \
    }                                                                            \
} while (0)

__global__ __launch_bounds__(256, 2)
void gemm_qkv(const unsigned short* __restrict__ xb,
              const unsigned short* __restrict__ wt,
              unsigned short* __restrict__ qbuf,
              unsigned short* __restrict__ kbuf,
              unsigned short* __restrict__ vtbuf) {
    const int sel = blockIdx.y;
    const int m0 = blockIdx.x * 128;
    const int t = threadIdx.x;
    const int lane = t & 63;
    const int w = t >> 6;
    const int wr = w >> 1;
    const int wc = w & 1;
    const int ln15 = lane & 15;
    const int g = lane >> 4;

    __shared__ __align__(16) unsigned short X0s[128 * 32];
    __shared__ __align__(16) unsigned short W0s[224 * 32];
    __shared__ __align__(16) unsigned short X1s[128 * 32];
    __shared__ __align__(16) unsigned short W1s[224 * 32];

    const unsigned short* wsel = wt + (size_t)sel * EP * KP;

    f32x4 acc[4][7];
#pragma unroll
    for (int i = 0; i < 4; ++i)
#pragma unroll
        for (int j = 0; j < 7; ++j) acc[i][j] = (f32x4)0.0f;

    const int rS = lane >> 2;            // staging row within 16-row chunk
    const int pS = lane & 3;             // staging physical granule

    STAGE(X0s, W0s, 0);
    __syncthreads();
#pragma unroll
    for (int p = 0; p < 12; ++p) {
        STAGE(X1s, W1s, 2 * p + 1);
        COMPUTE(X0s, W0s);
        __syncthreads();
        STAGE(X0s, W0s, 2 * p + 2);
        COMPUTE(X1s, W1s);
        __syncthreads();
    }
    STAGE(X1s, W1s, 25);
    COMPUTE(X0s, W0s);                   // kk = 24
    __syncthreads();
    COMPUTE(X1s, W1s);                   // kk = 25

    // epilogue: gelu + store; V padding col 200 <- 1.0 (ones-column: PV
    // MFMA computes softmax denominators for free in attn)
#pragma unroll
    for (int rf = 0; rf < 4; ++rf) {
        const int row = m0 + wr * 64 + rf * 16 + g * 4;
#pragma unroll
        for (int cf = 0; cf < 7; ++cf) {
            const int col = wc * 112 + cf * 16 + ln15;
            if (sel == 0) {
#pragma unroll
                for (int tt = 0; tt < 4; ++tt)
                    qbuf[(size_t)(row + tt) * EP + col] =
                        f2bf(gelu_fast(acc[rf][cf][tt]) * QSCL);
            } else if (sel == 1) {
#pragma unroll
                for (int tt = 0; tt < 4; ++tt)
                    kbuf[(size_t)(row + tt) * KSP + col] = f2bf(gelu_fast(acc[rf][cf][tt]));
            } else {
                const int bb = row >> 11, s = row & 2047;
                ushort4 pk;
                if (col == 200) {
                    pk.x = 0x3F80; pk.y = 0x3F80; pk.z = 0x3F80; pk.w = 0x3F80;
                } else {
                    pk.x = f2bf(gelu_fast(acc[rf][cf][0]));
                    pk.y = f2bf(gelu_fast(acc[rf][cf][1]));
                    pk.z = f2bf(gelu_fast(acc[rf][cf][2]));
                    pk.w = f2bf(gelu_fast(acc[rf][cf][3]));
                }
                *reinterpret_cast<ushort4*>(
                    &vtbuf[((size_t)(bb * EP + col)) * S_ + s]) = pk;
            }
        }
    }
}

// ---------------- Stage 2: flash attention ----------------
// BQ=64, 4 waves x 16 q-rows (256 thr), grid 512 -> 2 blocks/CU (LDS 72.5KB).
// K LDS double-buffered with FULL-spread swizzle phys = logical ^ ((row*4)&31).
// V NOT staged: read straight from vtbuf (L2-hot: 2 batches/XCD = 1.8MB < 4MB).
// ~115 VGPR -> no spill. R16 bug was the launch grid (256 instead of 512 ->
// odd batches never computed); fixed to 512.
#define BQ  64
#define BKV 64

#define ASTAGE(KB, KT) do {                                                      \
    const int kv0s = (KT) * BKV;                                                 \
    const int r_in = lane >> 5;                                                  \
    const int p = lane & 31;                                                     \
    _Pragma("unroll")                                                            \
    for (int i = 0; i < 8; ++i) {                                                \
        const int j = w * 8 + i;                                                 \
        const int row = 2 * j + r_in;                                            \
        gload_lds16(kb_b + (size_t)(kv0s + row) * KSP + ((p ^ ((row << 2) & 31)) * 8),\
                    &KB[j * 512]);                                               \
    }                                                                            \
} while (0)

#define ACOMPUTE(KB, KT) do {                                                    \
    const int kv0s = (KT) * BKV;                                                 \
    f32x4 sacc[4];                                                               \
    _Pragma("unroll")                                                            \
    for (int n = 0; n < 4; ++n) {                                                \
        f32x4 a = (f32x4)0.0f;                                                   \
        const int krow = n * 16 + ln15;                                          \
        const unsigned short* kr = &KB[krow * KSP];                              \
        const int rx = (krow << 2) & 31;                                         \
        _Pragma("unroll")                                                        \
        for (int s = 0; s < 7; ++s) {                                            \
            short8 bf = *reinterpret_cast<const short8*>(                        \
                kr + (((s * 4 + g) ^ rx) * 8));                                  \
            a = __builtin_amdgcn_mfma_f32_16x16x32_bf16(qf[s], bf, a, 0, 0, 0);  \
        }                                                                        \
        sacc[n] = a;                                                             \
    }                                                                            \
    _Pragma("unroll")                                                            \
    for (int n = 0; n < 4; ++n)                                                  \
        _Pragma("unroll")                                                        \
        for (int tt = 0; tt < 4; ++tt)                                           \
            Plds[w][g * 4 + tt][n * 16 + ln15] = f2bf(exp2_fast(sacc[n][tt]));   \
    short8 pf0 = *reinterpret_cast<const short8*>(&Plds[w][ln15][g * 8]);        \
    short8 pf1 = *reinterpret_cast<const short8*>(&Plds[w][ln15][32 + g * 8]);   \
    _Pragma("unroll")                                                            \
    for (int n = 0; n < 14; ++n) {                                               \
        const int vrow = n * 16 + ln15;                                          \
        const unsigned short* vr = vt_b + (size_t)vrow * S_ + kv0s;              \
        short8 b0 = *reinterpret_cast<const short8*>(vr + g * 8);                \
        short8 b1 = *reinterpret_cast<const short8*>(vr + 32 + g * 8);           \
        o[n] = __builtin_amdgcn_mfma_f32_16x16x32_bf16(pf0, b0, o[n], 0, 0, 0);  \
        o[n] = __builtin_amdgcn_mfma_f32_16x16x32_bf16(pf1, b1, o[n], 0, 0, 0);  \
    }                                                                            \
} while (0)

__global__ __launch_bounds__(256, 2)
void attn_kernel(const unsigned short* __restrict__ qbuf,
                 const unsigned short* __restrict__ kbuf,
                 const unsigned short* __restrict__ vtbuf,
                 float* __restrict__ out) {
    // XCD-aware role remap: XCD c serves batches {2c, 2c+1} (K/V 1.8MB < 4MB L2)
    const int id = blockIdx.x;            // 0..511
    const int slot = id >> 3;             // 0..63
    const int b = 2 * (id & 7) + (slot >> 5);
    const int q0 = (slot & 31) * BQ;
    const int t = threadIdx.x;
    const int lane = t & 63;
    const int w = t >> 6;                 // 0..3
    const int ln15 = lane & 15;
    const int g = lane >> 4;              // 0..3

    __shared__ __align__(16) unsigned short Ks[2][BKV * KSP];   // 2 x 32KB
    __shared__ __align__(16) unsigned short Plds[4][16][68];    // 8.5KB

    // Q fragments: 16 rows per wave (pre-scaled by scale*log2e)
    short8 qf[7];
    {
        const unsigned short* qp =
            qbuf + (size_t)(b * S_ + q0 + w * 16 + ln15) * EP + g * 8;
#pragma unroll
        for (int s = 0; s < 7; ++s)
            qf[s] = *reinterpret_cast<const short8*>(qp + s * 32);
    }

    f32x4 o[14];
#pragma unroll
    for (int i = 0; i < 14; ++i) o[i] = (f32x4)0.0f;

    const unsigned short* kb_b = kbuf + (size_t)b * S_ * KSP;
    const unsigned short* vt_b = vtbuf + (size_t)b * EP * S_;

    ASTAGE(Ks[0], 0);
    __syncthreads();
    for (int kt = 0; kt < S_ / BKV - 1; ++kt) {
        const int cur = kt & 1;
        ASTAGE(Ks[cur ^ 1], kt + 1);
        ACOMPUTE(Ks[cur], kt);
        __syncthreads();
    }
    ACOMPUTE(Ks[1], S_ / BKV - 1);        // tile 31 (odd -> buffer 1)

    // epilogue: l = o[12] at col 200 (ln15==8); broadcast, normalize, store
    {
        float l[4];
#pragma unroll
        for (int tt = 0; tt < 4; ++tt)
            l[tt] = __shfl(o[12][tt], (lane & 48) + 8, 64);
#pragma unroll
        for (int tt = 0; tt < 4; ++tt) {
            const float inv = 1.0f / l[tt];
            const int row = q0 + w * 16 + g * 4 + tt;
            float* op = out + (size_t)(b * S_ + row) * E_;
#pragma unroll
            for (int n = 0; n < 13; ++n) {
                const int e = n * 16 + ln15;
                if (e < E_) op[e] = o[n][tt] * inv;
            }
        }
    }
}

extern "C" void kernel_launch(void* const* d_in, const int* in_sizes, int n_in,
                              void* d_out, int out_size, void* d_ws, size_t ws_size,
                              hipStream_t stream) {
    const float* x  = (const float*)d_in[0];
    const float* Wq = (const float*)d_in[1];
    const float* Wk = (const float*)d_in[2];
    const float* Wv = (const float*)d_in[3];
    float* out = (float*)d_out;

    unsigned short* xb    = (unsigned short*)d_ws;                 // [M_][KP]
    unsigned short* wt    = xb + (size_t)M_ * KP;                  // [3][EP][KP]
    unsigned short* qbuf  = wt + (size_t)3 * EP * KP;              // [M_][EP]
    unsigned short* kbuf  = qbuf + (size_t)M_ * EP;                // [M_][KSP]
    unsigned short* vtbuf = kbuf + (size_t)M_ * KSP;               // [B_][EP][S_]

    prep_x<<<dim3(M_ * (KP / 8) / 256), 256, 0, stream>>>(x, xb);
    prep_w<<<dim3(3 * EP * KP / 256), 256, 0, stream>>>(Wq, Wk, Wv, wt);
    gemm_qkv<<<dim3(256, 3), 256, 0, stream>>>(xb, wt, qbuf, kbuf, vtbuf);
    attn_kernel<<<dim3((S_ / BQ) * B_), 256, 0, stream>>>(qbuf, kbuf, vtbuf, out);
}

// Round 18
// 194.560 us; speedup vs baseline: 1.5156x; 1.5156x over previous
//
#include <hip/hip_runtime.h>
#include <hip/hip_bf16.h>

#define B_  16
#define S_  2048
#define F_  800
#define E_  200
#define EP  224          // padded E (multiple of 32)
#define KP  832          // padded K (26 * 32)
#define KSP 256          // kbuf row pitch in shorts (32 x 16B slots, pow2 for swizzle)
#define M_  (B_ * S_)    // 32768

typedef __attribute__((ext_vector_type(8))) short short8;
typedef __attribute__((ext_vector_type(4))) float f32x4;

// scale = 1/sqrt(960); folded with log2(e) into Q so softmax runs in exp2 domain
#define QSCL (0.03227486121839514f * 1.4426950408889634f)

__device__ __forceinline__ unsigned short f2bf(float f) {
    __hip_bfloat16 h = __float2bfloat16(f);
    return *reinterpret_cast<unsigned short*>(&h);
}

__device__ __forceinline__ float exp2_fast(float x) {
    float r;
    asm("v_exp_f32 %0, %1" : "=v"(r) : "v"(x));
    return r;
}

__device__ __forceinline__ float rcp_fast(float x) {
    float r;
    asm("v_rcp_f32 %0, %1" : "=v"(r) : "v"(x));
    return r;
}

// tanh-form GELU (max |err| vs exact ~5e-4, below bf16 noise here)
__device__ __forceinline__ float gelu_fast(float x) {
    const float i = x + 0.044715f * x * x * x;
    const float z = 2.302265314f * i;              // 2*0.79788456*log2(e) * i
    return x * rcp_fast(1.0f + exp2_fast(-z));
}

__device__ __forceinline__ void gload_lds16(const void* g, void* l) {
    __builtin_amdgcn_global_load_lds(
        (const __attribute__((address_space(1))) unsigned int*)g,
        (__attribute__((address_space(3))) unsigned int*)l, 16, 0, 0);
}

// ---------------- prep: X fp32 -> bf16 padded [M][KP] ----------------
__global__ __launch_bounds__(256)
void prep_x(const float* __restrict__ x, unsigned short* __restrict__ xb) {
    const int id = blockIdx.x * 256 + threadIdx.x;
    const int r  = id / (KP / 8);
    const int c8 = id % (KP / 8);
    ushort4 lo = {0, 0, 0, 0}, hi = {0, 0, 0, 0};
    if (c8 < F_ / 8) {
        const float4 a = *reinterpret_cast<const float4*>(x + (size_t)r * F_ + c8 * 8);
        const float4 b = *reinterpret_cast<const float4*>(x + (size_t)r * F_ + c8 * 8 + 4);
        lo.x = f2bf(a.x); lo.y = f2bf(a.y); lo.z = f2bf(a.z); lo.w = f2bf(a.w);
        hi.x = f2bf(b.x); hi.y = f2bf(b.y); hi.z = f2bf(b.z); hi.w = f2bf(b.w);
    }
    unsigned short* dst = xb + (size_t)r * KP + c8 * 8;
    *reinterpret_cast<ushort4*>(dst) = lo;
    *reinterpret_cast<ushort4*>(dst + 4) = hi;
}

// ---------------- prep: W^T bf16 padded wt[3][EP][KP] ----------------
__global__ __launch_bounds__(256)
void prep_w(const float* __restrict__ Wq, const float* __restrict__ Wk,
            const float* __restrict__ Wv, unsigned short* __restrict__ wt) {
    const int id = blockIdx.x * 256 + threadIdx.x;
    const int sel = id / (EP * KP);
    const int rem = id % (EP * KP);
    const int e = rem / KP;
    const int k = rem % KP;
    const float* W = (sel == 0) ? Wq : ((sel == 1) ? Wk : Wv);
    float v = (e < E_ && k < F_) ? W[(size_t)k * E_ + e] : 0.0f;
    wt[id] = f2bf(v);
}

// ---------------- Stage 1 GEMM: Q/K/V = gelu(Xb @ W) ----------------
// (unchanged from the round-13/15 passing source)
#define STAGE(XB, WB, KK) do {                                                   \
    const int k0s = (KK) * 32;                                                   \
    _Pragma("unroll")                                                            \
    for (int i = 0; i < 2; ++i) {                                                \
        const int j = w * 2 + i;                                                 \
        const int row = 16 * j + rS;                                             \
        gload_lds16(xb + (size_t)(m0 + row) * KP + k0s + ((pS ^ (row & 3)) * 8), \
                    &XB[j * 512]);                                               \
    }                                                                            \
    _Pragma("unroll")                                                            \
    for (int i = 0; i < 4; ++i) {                                                \
        const int j = i * 4 + w;                                                 \
        if (j < 14) {                                                            \
            const int row = 16 * j + rS;                                         \
            gload_lds16(wsel + (size_t)row * KP + k0s + ((pS ^ (row & 3)) * 8),  \
                        &WB[j * 512]);                                           \
        }                                                                        \
    }                                                                            \
} while (0)

#define COMPUTE(XB, WB) do {                                                     \
    short8 afr[4];                                                               \
    _Pragma("unroll")                                                            \
    for (int rf = 0; rf < 4; ++rf) {                                             \
        const int row = wr * 64 + rf * 16 + ln15;                                \
        afr[rf] = *reinterpret_cast<const short8*>(                              \
            &XB[row * 32 + ((g ^ (row & 3)) * 8)]);                              \
    }                                                                            \
    _Pragma("unroll")                                                            \
    for (int cf = 0; cf < 7; ++cf) {                                             \
        const int row = wc * 112 + cf * 16 + ln15;                               \
        short8 bfr = *reinterpret_cast<const short8*>(                           \
            &WB[row * 32 + ((g ^ (row & 3)) * 8)]);                              \
        _Pragma("unroll")                                                        \
        for (int rf = 0; rf < 4; ++rf)                                           \
            acc[rf][cf] = __builtin_amdgcn_mfma_f32_16x16x32_bf16(               \
                afr[rf], bfr, acc[rf][cf], 0, 0, 0);                             \
    }                                                                            \
} while (0)

__global__ __launch_bounds__(256, 2)
void gemm_qkv(const unsigned short* __restrict__ xb,
              const unsigned short* __restrict__ wt,
              unsigned short* __restrict__ qbuf,
              unsigned short* __restrict__ kbuf,
              unsigned short* __restrict__ vtbuf) {
    const int sel = blockIdx.y;
    const int m0 = blockIdx.x * 128;
    const int t = threadIdx.x;
    const int lane = t & 63;
    const int w = t >> 6;
    const int wr = w >> 1;
    const int wc = w & 1;
    const int ln15 = lane & 15;
    const int g = lane >> 4;

    __shared__ __align__(16) unsigned short X0s[128 * 32];
    __shared__ __align__(16) unsigned short W0s[224 * 32];
    __shared__ __align__(16) unsigned short X1s[128 * 32];
    __shared__ __align__(16) unsigned short W1s[224 * 32];

    const unsigned short* wsel = wt + (size_t)sel * EP * KP;

    f32x4 acc[4][7];
#pragma unroll
    for (int i = 0; i < 4; ++i)
#pragma unroll
        for (int j = 0; j < 7; ++j) acc[i][j] = (f32x4)0.0f;

    const int rS = lane >> 2;            // staging row within 16-row chunk
    const int pS = lane & 3;             // staging physical granule

    STAGE(X0s, W0s, 0);
    __syncthreads();
#pragma unroll
    for (int p = 0; p < 12; ++p) {
        STAGE(X1s, W1s, 2 * p + 1);
        COMPUTE(X0s, W0s);
        __syncthreads();
        STAGE(X0s, W0s, 2 * p + 2);
        COMPUTE(X1s, W1s);
        __syncthreads();
    }
    STAGE(X1s, W1s, 25);
    COMPUTE(X0s, W0s);                   // kk = 24
    __syncthreads();
    COMPUTE(X1s, W1s);                   // kk = 25

    // epilogue: gelu + store; V padding col 200 <- 1.0 (ones-column: PV
    // MFMA computes softmax denominators for free in attn)
#pragma unroll
    for (int rf = 0; rf < 4; ++rf) {
        const int row = m0 + wr * 64 + rf * 16 + g * 4;
#pragma unroll
        for (int cf = 0; cf < 7; ++cf) {
            const int col = wc * 112 + cf * 16 + ln15;
            if (sel == 0) {
#pragma unroll
                for (int tt = 0; tt < 4; ++tt)
                    qbuf[(size_t)(row + tt) * EP + col] =
                        f2bf(gelu_fast(acc[rf][cf][tt]) * QSCL);
            } else if (sel == 1) {
#pragma unroll
                for (int tt = 0; tt < 4; ++tt)
                    kbuf[(size_t)(row + tt) * KSP + col] = f2bf(gelu_fast(acc[rf][cf][tt]));
            } else {
                const int bb = row >> 11, s = row & 2047;
                ushort4 pk;
                if (col == 200) {
                    pk.x = 0x3F80; pk.y = 0x3F80; pk.z = 0x3F80; pk.w = 0x3F80;
                } else {
                    pk.x = f2bf(gelu_fast(acc[rf][cf][0]));
                    pk.y = f2bf(gelu_fast(acc[rf][cf][1]));
                    pk.z = f2bf(gelu_fast(acc[rf][cf][2]));
                    pk.w = f2bf(gelu_fast(acc[rf][cf][3]));
                }
                *reinterpret_cast<ushort4*>(
                    &vtbuf[((size_t)(bb * EP + col)) * S_ + s]) = pk;
            }
        }
    }
}

// ---------------- Stage 2: flash attention (R15 structure, BKV=32) --------
// BQ=128, 8 waves x 16 q-rows (512 thr), BKV=32 double-buffered K AND V
// (R17's direct-V global reads were latency-bound: MfmaUtil 10.6%).
// LDS 71.7KB -> 2 blocks/CU = 4 waves/SIMD. ~80 VGPR -> no spill.
// Proven swizzles: K slot p^(row&7); V 16-row chunks slot p^(row&3) (gemm idiom).
#define BQ  128
#define BKV 32

#define ASTAGE(KB, VB, KT) do {                                                  \
    const int kv0s = (KT) * BKV;                                                 \
    {   /* K: 16 x 1KB chunks, 2 per wave, 2 rows each */                        \
        const int r_in = lane >> 5;                                              \
        const int p = lane & 31;                                                 \
        _Pragma("unroll")                                                        \
        for (int i = 0; i < 2; ++i) {                                            \
            const int j = w * 2 + i;                                             \
            const int row = 2 * j + r_in;                                        \
            gload_lds16(kb_b + (size_t)(kv0s + row) * KSP + ((p ^ (row & 7)) * 8),\
                        &KB[j * 512]);                                           \
        }                                                                        \
    }                                                                            \
    {   /* V: 14 x 1KB chunks, 16 rows each (row = 64B = 4 granules) */          \
        const int r_in = lane >> 2;                                              \
        const int p = lane & 3;                                                  \
        _Pragma("unroll")                                                        \
        for (int i = 0; i < 2; ++i) {                                            \
            const int j = i * 8 + w;                                             \
            if (j < 14) {                                                        \
                const int row = 16 * j + r_in;                                   \
                gload_lds16(vt_b + (size_t)row * S_ + kv0s + ((p ^ (row & 3)) * 8),\
                            &VB[j * 512]);                                       \
            }                                                                    \
        }                                                                        \
    }                                                                            \
} while (0)

#define ACOMPUTE(KB, VB) do {                                                    \
    f32x4 sacc[2];                                                               \
    _Pragma("unroll")                                                            \
    for (int n = 0; n < 2; ++n) {                                                \
        f32x4 a = (f32x4)0.0f;                                                   \
        const int krow = n * 16 + ln15;                                          \
        const unsigned short* kr = &KB[krow * KSP];                              \
        const int rx = krow & 7;                                                 \
        _Pragma("unroll")                                                        \
        for (int s = 0; s < 7; ++s) {                                            \
            short8 bf = *reinterpret_cast<const short8*>(                        \
                kr + (((s * 4 + g) ^ rx) * 8));                                  \
            a = __builtin_amdgcn_mfma_f32_16x16x32_bf16(qf[s], bf, a, 0, 0, 0);  \
        }                                                                        \
        sacc[n] = a;                                                             \
    }                                                                            \
    _Pragma("unroll")                                                            \
    for (int n = 0; n < 2; ++n)                                                  \
        _Pragma("unroll")                                                        \
        for (int tt = 0; tt < 4; ++tt)                                           \
            Plds[w][g * 4 + tt][n * 16 + ln15] = f2bf(exp2_fast(sacc[n][tt]));   \
    short8 pf = *reinterpret_cast<const short8*>(&Plds[w][ln15][g * 8]);         \
    _Pragma("unroll")                                                            \
    for (int n = 0; n < 14; ++n) {                                               \
        const int vrow = n * 16 + ln15;                                          \
        short8 b0 = *reinterpret_cast<const short8*>(                            \
            &VB[vrow * 32 + ((g ^ (vrow & 3)) * 8)]);                            \
        o[n] = __builtin_amdgcn_mfma_f32_16x16x32_bf16(pf, b0, o[n], 0, 0, 0);   \
    }                                                                            \
} while (0)

__global__ __launch_bounds__(512, 2)
void attn_kernel(const unsigned short* __restrict__ qbuf,
                 const unsigned short* __restrict__ kbuf,
                 const unsigned short* __restrict__ vtbuf,
                 float* __restrict__ out) {
    // XCD-aware role remap: XCD c serves batches {2c, 2c+1} (K/V 1.8MB < 4MB L2)
    const int id = blockIdx.x;            // 0..255
    const int slot = id >> 3;             // 0..31
    const int b = 2 * (id & 7) + (slot >> 4);
    const int q0 = (slot & 15) * BQ;
    const int t = threadIdx.x;
    const int lane = t & 63;
    const int w = t >> 6;                 // 0..7
    const int ln15 = lane & 15;
    const int g = lane >> 4;              // 0..3

    __shared__ __align__(16) unsigned short Ks[2][BKV * KSP];   // 2 x 16KB
    __shared__ __align__(16) unsigned short Vts[2][EP * BKV];   // 2 x 14KB
    __shared__ __align__(16) unsigned short Plds[8][16][40];    // 10KB

    // Q fragments: 16 rows per wave (pre-scaled by scale*log2e)
    short8 qf[7];
    {
        const unsigned short* qp =
            qbuf + (size_t)(b * S_ + q0 + w * 16 + ln15) * EP + g * 8;
#pragma unroll
        for (int s = 0; s < 7; ++s)
            qf[s] = *reinterpret_cast<const short8*>(qp + s * 32);
    }

    f32x4 o[14];
#pragma unroll
    for (int i = 0; i < 14; ++i) o[i] = (f32x4)0.0f;

    const unsigned short* kb_b = kbuf + (size_t)b * S_ * KSP;
    const unsigned short* vt_b = vtbuf + (size_t)b * EP * S_;

    ASTAGE(Ks[0], Vts[0], 0);
    __syncthreads();
    for (int kt = 0; kt < S_ / BKV - 1; ++kt) {
        const int cur = kt & 1;
        ASTAGE(Ks[cur ^ 1], Vts[cur ^ 1], kt + 1);
        ACOMPUTE(Ks[cur], Vts[cur]);
        __syncthreads();
    }
    ACOMPUTE(Ks[1], Vts[1]);              // tile 63 (odd -> buffer 1)

    // epilogue: l = o[12] at col 200 (ln15==8); broadcast, normalize, store
    {
        float l[4];
#pragma unroll
        for (int tt = 0; tt < 4; ++tt)
            l[tt] = __shfl(o[12][tt], (lane & 48) + 8, 64);
#pragma unroll
        for (int tt = 0; tt < 4; ++tt) {
            const float inv = 1.0f / l[tt];
            const int row = q0 + w * 16 + g * 4 + tt;
            float* op = out + (size_t)(b * S_ + row) * E_;
#pragma unroll
            for (int n = 0; n < 13; ++n) {
                const int e = n * 16 + ln15;
                if (e < E_) op[e] = o[n][tt] * inv;
            }
        }
    }
}

extern "C" void kernel_launch(void* const* d_in, const int* in_sizes, int n_in,
                              void* d_out, int out_size, void* d_ws, size_t ws_size,
                              hipStream_t stream) {
    const float* x  = (const float*)d_in[0];
    const float* Wq = (const float*)d_in[1];
    const float* Wk = (const float*)d_in[2];
    const float* Wv = (const float*)d_in[3];
    float* out = (float*)d_out;

    unsigned short* xb    = (unsigned short*)d_ws;                 // [M_][KP]
    unsigned short* wt    = xb + (size_t)M_ * KP;                  // [3][EP][KP]
    unsigned short* qbuf  = wt + (size_t)3 * EP * KP;              // [M_][EP]
    unsigned short* kbuf  = qbuf + (size_t)M_ * EP;                // [M_][KSP]
    unsigned short* vtbuf = kbuf + (size_t)M_ * KSP;               // [B_][EP][S_]

    prep_x<<<dim3(M_ * (KP / 8) / 256), 256, 0, stream>>>(x, xb);
    prep_w<<<dim3(3 * EP * KP / 256), 256, 0, stream>>>(Wq, Wk, Wv, wt);
    gemm_qkv<<<dim3(256, 3), 256, 0, stream>>>(xb, wt, qbuf, kbuf, vtbuf);
    attn_kernel<<<dim3((S_ / BQ) * B_), 512, 0, stream>>>(qbuf, kbuf, vtbuf, out);
}

// Round 21
// 189.074 us; speedup vs baseline: 1.5596x; 1.0290x over previous
//
#include <hip/hip_runtime.h>
#include <hip/hip_bf16.h>

#define B_  16
#define S_  2048
#define F_  800
#define E_  200
#define EP  224          // padded E (multiple of 32)
#define KP  832          // padded K (26 * 32)
#define KSP 256          // kbuf row pitch in shorts (32 x 16B slots, pow2 for swizzle)
#define M_  (B_ * S_)    // 32768

typedef __attribute__((ext_vector_type(8))) short short8;
typedef __attribute__((ext_vector_type(4))) float f32x4;

// scale = 1/sqrt(960); folded with log2(e) into Q so softmax runs in exp2 domain
#define QSCL (0.03227486121839514f * 1.4426950408889634f)

__device__ __forceinline__ unsigned short f2bf(float f) {
    __hip_bfloat16 h = __float2bfloat16(f);
    return *reinterpret_cast<unsigned short*>(&h);
}

__device__ __forceinline__ float exp2_fast(float x) {
    float r;
    asm("v_exp_f32 %0, %1" : "=v"(r) : "v"(x));
    return r;
}

__device__ __forceinline__ float rcp_fast(float x) {
    float r;
    asm("v_rcp_f32 %0, %1" : "=v"(r) : "v"(x));
    return r;
}

// tanh-form GELU (max |err| vs exact ~5e-4, below bf16 noise here)
__device__ __forceinline__ float gelu_fast(float x) {
    const float i = x + 0.044715f * x * x * x;
    const float z = 2.302265314f * i;              // 2*0.79788456*log2(e) * i
    return x * rcp_fast(1.0f + exp2_fast(-z));
}

__device__ __forceinline__ void gload_lds16(const void* g, void* l) {
    __builtin_amdgcn_global_load_lds(
        (const __attribute__((address_space(1))) unsigned int*)g,
        (__attribute__((address_space(3))) unsigned int*)l, 16, 0, 0);
}

// ---------------- prep: X fp32 -> bf16 padded [M][KP] ----------------
__global__ __launch_bounds__(256)
void prep_x(const float* __restrict__ x, unsigned short* __restrict__ xb) {
    const int id = blockIdx.x * 256 + threadIdx.x;
    const int r  = id / (KP / 8);
    const int c8 = id % (KP / 8);
    ushort4 lo = {0, 0, 0, 0}, hi = {0, 0, 0, 0};
    if (c8 < F_ / 8) {
        const float4 a = *reinterpret_cast<const float4*>(x + (size_t)r * F_ + c8 * 8);
        const float4 b = *reinterpret_cast<const float4*>(x + (size_t)r * F_ + c8 * 8 + 4);
        lo.x = f2bf(a.x); lo.y = f2bf(a.y); lo.z = f2bf(a.z); lo.w = f2bf(a.w);
        hi.x = f2bf(b.x); hi.y = f2bf(b.y); hi.z = f2bf(b.z); hi.w = f2bf(b.w);
    }
    unsigned short* dst = xb + (size_t)r * KP + c8 * 8;
    *reinterpret_cast<ushort4*>(dst) = lo;
    *reinterpret_cast<ushort4*>(dst + 4) = hi;
}

// ---------------- prep: W^T bf16 padded wt[3][EP][KP] ----------------
__global__ __launch_bounds__(256)
void prep_w(const float* __restrict__ Wq, const float* __restrict__ Wk,
            const float* __restrict__ Wv, unsigned short* __restrict__ wt) {
    const int id = blockIdx.x * 256 + threadIdx.x;
    const int sel = id / (EP * KP);
    const int rem = id % (EP * KP);
    const int e = rem / KP;
    const int k = rem % KP;
    const float* W = (sel == 0) ? Wq : ((sel == 1) ? Wk : Wv);
    float v = (e < E_ && k < F_) ? W[(size_t)k * E_ + e] : 0.0f;
    wt[id] = f2bf(v);
}

// ---------------- Stage 1 GEMM: Q/K/V = gelu(Xb @ W) ----------------
// (unchanged from the round-13/15 passing source)
#define STAGE(XB, WB, KK) do {                                                   \
    const int k0s = (KK) * 32;                                                   \
    _Pragma("unroll")                                                            \
    for (int i = 0; i < 2; ++i) {                                                \
        const int j = w * 2 + i;                                                 \
        const int row = 16 * j + rS;                                             \
        gload_lds16(xb + (size_t)(m0 + row) * KP + k0s + ((pS ^ (row & 3)) * 8), \
                    &XB[j * 512]);                                               \
    }                                                                            \
    _Pragma("unroll")                                                            \
    for (int i = 0; i < 4; ++i) {                                                \
        const int j = i * 4 + w;                                                 \
        if (j < 14) {                                                            \
            const int row = 16 * j + rS;                                         \
            gload_lds16(wsel + (size_t)row * KP + k0s + ((pS ^ (row & 3)) * 8),  \
                        &WB[j * 512]);                                           \
        }                                                                        \
    }                                                                            \
} while (0)

#define COMPUTE(XB, WB) do {                                                     \
    short8 afr[4];                                                               \
    _Pragma("unroll")                                                            \
    for (int rf = 0; rf < 4; ++rf) {                                             \
        const int row = wr * 64 + rf * 16 + ln15;                                \
        afr[rf] = *reinterpret_cast<const short8*>(                              \
            &XB[row * 32 + ((g ^ (row & 3)) * 8)]);                              \
    }                                                                            \
    _Pragma("unroll")                                                            \
    for (int cf = 0; cf < 7; ++cf) {                                             \
        const int row = wc * 112 + cf * 16 + ln15;                               \
        short8 bfr = *reinterpret_cast<const short8*>(                           \
            &WB[row * 32 + ((g ^ (row & 3)) * 8)]);                              \
        _Pragma("unroll")                                                        \
        for (int rf = 0; rf < 4; ++rf)                                           \
            acc[rf][cf] = __builtin_amdgcn_mfma_f32_16x16x32_bf16(               \
                afr[rf], bfr, acc[rf][cf], 0, 0, 0);                             \
    }                                                                            \
} while (0)

__global__ __launch_bounds__(256, 2)
void gemm_qkv(const unsigned short* __restrict__ xb,
              const unsigned short* __restrict__ wt,
              unsigned short* __restrict__ qbuf,
              unsigned short* __restrict__ kbuf,
              unsigned short* __restrict__ vtbuf) {
    const int sel = blockIdx.y;
    const int m0 = blockIdx.x * 128;
    const int t = threadIdx.x;
    const int lane = t & 63;
    const int w = t >> 6;
    const int wr = w >> 1;
    const int wc = w & 1;
    const int ln15 = lane & 15;
    const int g = lane >> 4;

    __shared__ __align__(16) unsigned short X0s[128 * 32];
    __shared__ __align__(16) unsigned short W0s[224 * 32];
    __shared__ __align__(16) unsigned short X1s[128 * 32];
    __shared__ __align__(16) unsigned short W1s[224 * 32];

    const unsigned short* wsel = wt + (size_t)sel * EP * KP;

    f32x4 acc[4][7];
#pragma unroll
    for (int i = 0; i < 4; ++i)
#pragma unroll
        for (int j = 0; j < 7; ++j) acc[i][j] = (f32x4)0.0f;

    const int rS = lane >> 2;            // staging row within 16-row chunk
    const int pS = lane & 3;             // staging physical granule

    STAGE(X0s, W0s, 0);
    __syncthreads();
#pragma unroll
    for (int p = 0; p < 12; ++p) {
        STAGE(X1s, W1s, 2 * p + 1);
        COMPUTE(X0s, W0s);
        __syncthreads();
        STAGE(X0s, W0s, 2 * p + 2);
        COMPUTE(X1s, W1s);
        __syncthreads();
    }
    STAGE(X1s, W1s, 25);
    COMPUTE(X0s, W0s);                   // kk = 24
    __syncthreads();
    COMPUTE(X1s, W1s);                   // kk = 25

    // epilogue: gelu + store; V padding col 200 <- 1.0 (kept, harmless)
#pragma unroll
    for (int rf = 0; rf < 4; ++rf) {
        const int row = m0 + wr * 64 + rf * 16 + g * 4;
#pragma unroll
        for (int cf = 0; cf < 7; ++cf) {
            const int col = wc * 112 + cf * 16 + ln15;
            if (sel == 0) {
#pragma unroll
                for (int tt = 0; tt < 4; ++tt)
                    qbuf[(size_t)(row + tt) * EP + col] =
                        f2bf(gelu_fast(acc[rf][cf][tt]) * QSCL);
            } else if (sel == 1) {
#pragma unroll
                for (int tt = 0; tt < 4; ++tt)
                    kbuf[(size_t)(row + tt) * KSP + col] = f2bf(gelu_fast(acc[rf][cf][tt]));
            } else {
                const int bb = row >> 11, s = row & 2047;
                ushort4 pk;
                if (col == 200) {
                    pk.x = 0x3F80; pk.y = 0x3F80; pk.z = 0x3F80; pk.w = 0x3F80;
                } else {
                    pk.x = f2bf(gelu_fast(acc[rf][cf][0]));
                    pk.y = f2bf(gelu_fast(acc[rf][cf][1]));
                    pk.z = f2bf(gelu_fast(acc[rf][cf][2]));
                    pk.w = f2bf(gelu_fast(acc[rf][cf][3]));
                }
                *reinterpret_cast<ushort4*>(
                    &vtbuf[((size_t)(bb * EP + col)) * S_ + s]) = pk;
            }
        }
    }
}

// ---------------- Stage 2: flash attention (cross-block E-split) ----------
// grid 512 = 256 (b,q0) x 2 E-halves. Block: 4 waves x 32 q-rows (A-reuse),
// BKV=32 dbuf, V tile = own 112 e-rows. LDS 58KB -> 2 blocks/CU (grid > #CU,
// so residency is actually used). Denominator via dn = mfma(P, ones): every
// lane holds its own row-sum, no shfl/handoff. launch_bounds(256,1): ~165
// VGPR, NO spill. Chunk counts: K 16 = 4 waves x (i<4, j=w*4+i);
// V 7 = (i<2, j=i*4+w)<7 — verified complete (R14's holes were the killer).
#define BQ  128
#define BKV 32

#define ASTAGE(KB, VB, KT) do {                                                  \
    const int kv0s = (KT) * BKV;                                                 \
    {   /* K: 16 x 1KB chunks, 4 per wave, 2 rows each (rows 0..31) */           \
        const int r_in = lane >> 5;                                              \
        const int p = lane & 31;                                                 \
        _Pragma("unroll")                                                        \
        for (int i = 0; i < 4; ++i) {                                            \
            const int j = w * 4 + i;                                             \
            const int row = 2 * j + r_in;                                        \
            gload_lds16(kb_b + (size_t)(kv0s + row) * KSP + ((p ^ (row & 7)) * 8),\
                        &KB[j * 512]);                                           \
        }                                                                        \
    }                                                                            \
    {   /* V: 7 x 1KB chunks, 16 local rows each (local rows 0..111) */          \
        const int r_in = lane >> 2;                                              \
        const int p = lane & 3;                                                  \
        _Pragma("unroll")                                                        \
        for (int i = 0; i < 2; ++i) {                                            \
            const int j = i * 4 + w;                                             \
            if (j < 7) {                                                         \
                const int lr = 16 * j + r_in;                                    \
                gload_lds16(vt_b + (size_t)(ehBase + lr) * S_ + kv0s +           \
                                ((p ^ (lr & 3)) * 8),                            \
                            &VB[j * 512]);                                       \
            }                                                                    \
        }                                                                        \
    }                                                                            \
} while (0)

#define ACOMPUTE(KB, VB) do {                                                    \
    short8 pf[2];                                                                \
    _Pragma("unroll")                                                            \
    for (int rf = 0; rf < 2; ++rf) {                                             \
        f32x4 sacc[2];                                                           \
        _Pragma("unroll")                                                        \
        for (int n = 0; n < 2; ++n) {                                            \
            f32x4 a = (f32x4)0.0f;                                               \
            const int krow = n * 16 + ln15;                                      \
            const unsigned short* kr = &KB[krow * KSP];                          \
            const int rx = krow & 7;                                             \
            _Pragma("unroll")                                                    \
            for (int s = 0; s < 7; ++s) {                                        \
                short8 bf = *reinterpret_cast<const short8*>(                    \
                    kr + (((s * 4 + g) ^ rx) * 8));                              \
                a = __builtin_amdgcn_mfma_f32_16x16x32_bf16(qf[rf][s], bf, a, 0, 0, 0); \
            }                                                                    \
            sacc[n] = a;                                                         \
        }                                                                        \
        _Pragma("unroll")                                                        \
        for (int n = 0; n < 2; ++n)                                              \
            _Pragma("unroll")                                                    \
            for (int tt = 0; tt < 4; ++tt)                                       \
                Plds[w][rf * 16 + g * 4 + tt][n * 16 + ln15] =                   \
                    f2bf(exp2_fast(sacc[n][tt]));                                \
        pf[rf] = *reinterpret_cast<const short8*>(&Plds[w][rf * 16 + ln15][g * 8]); \
        dn[rf] = __builtin_amdgcn_mfma_f32_16x16x32_bf16(pf[rf], ones8, dn[rf], 0, 0, 0); \
    }                                                                            \
    _Pragma("unroll")                                                            \
    for (int n = 0; n < 7; ++n) {                                                \
        const int lr = n * 16 + ln15;                                            \
        short8 b0 = *reinterpret_cast<const short8*>(                            \
            &VB[lr * 32 + ((g ^ (lr & 3)) * 8)]);                                \
        _Pragma("unroll")                                                        \
        for (int rf = 0; rf < 2; ++rf)                                           \
            o[rf][n] = __builtin_amdgcn_mfma_f32_16x16x32_bf16(pf[rf], b0, o[rf][n], 0, 0, 0); \
    }                                                                            \
} while (0)

__global__ __launch_bounds__(256, 1)
void attn_kernel(const unsigned short* __restrict__ qbuf,
                 const unsigned short* __restrict__ kbuf,
                 const unsigned short* __restrict__ vtbuf,
                 float* __restrict__ out) {
    // decode: 512 blocks; XCD-aware (id&7 spreads XCDs, K/V L2-local per batch)
    const int id = blockIdx.x;            // 0..511
    const int slot = id >> 3;             // 0..63
    const int eh = slot & 1;              // E-half: 0 -> e 0..111, 1 -> 112..223
    const int rest = slot >> 1;           // 0..31
    const int b = 2 * (id & 7) + (rest >> 4);
    const int q0 = (rest & 15) * BQ;
    const int ehBase = eh * 112;
    const int t = threadIdx.x;
    const int lane = t & 63;
    const int w = t >> 6;                 // 0..3
    const int ln15 = lane & 15;
    const int g = lane >> 4;              // 0..3

    __shared__ __align__(16) unsigned short Ks[2][BKV * KSP];   // 2 x 16KB
    __shared__ __align__(16) unsigned short Vts[2][112 * BKV];  // 2 x 7KB
    __shared__ __align__(16) unsigned short Plds[4][32][48];    // 12KB

    short8 ones8;
    {
        union { unsigned short u[8]; short8 s; } ou;
#pragma unroll
        for (int i = 0; i < 8; ++i) ou.u[i] = 0x3F80;   // bf16 1.0
        ones8 = ou.s;
    }

    // Q fragments: 32 rows per wave (pre-scaled by scale*log2e)
    short8 qf[2][7];
#pragma unroll
    for (int rf = 0; rf < 2; ++rf) {
        const unsigned short* qp =
            qbuf + (size_t)(b * S_ + q0 + w * 32 + rf * 16 + ln15) * EP + g * 8;
#pragma unroll
        for (int s = 0; s < 7; ++s)
            qf[rf][s] = *reinterpret_cast<const short8*>(qp + s * 32);
    }

    f32x4 o[2][7];
    f32x4 dn[2];
#pragma unroll
    for (int rf = 0; rf < 2; ++rf) {
        dn[rf] = (f32x4)0.0f;
#pragma unroll
        for (int i = 0; i < 7; ++i) o[rf][i] = (f32x4)0.0f;
    }

    const unsigned short* kb_b = kbuf + (size_t)b * S_ * KSP;
    const unsigned short* vt_b = vtbuf + (size_t)b * EP * S_;

    ASTAGE(Ks[0], Vts[0], 0);
    __syncthreads();
    for (int kt = 0; kt < S_ / BKV - 1; ++kt) {
        const int cur = kt & 1;
        ASTAGE(Ks[cur ^ 1], Vts[cur ^ 1], kt + 1);
        ACOMPUTE(Ks[cur], Vts[cur]);
        __syncthreads();
    }
    ACOMPUTE(Ks[1], Vts[1]);              // tile 63 (odd -> buffer 1)

    // epilogue: every lane holds its own rows' denominators in dn[rf][tt]
#pragma unroll
    for (int rf = 0; rf < 2; ++rf) {
#pragma unroll
        for (int tt = 0; tt < 4; ++tt) {
            const float inv = 1.0f / dn[rf][tt];
            const int row = q0 + w * 32 + rf * 16 + g * 4 + tt;
            float* op = out + (size_t)(b * S_ + row) * E_;
#pragma unroll
            for (int n = 0; n < 7; ++n) {
                const int e = ehBase + n * 16 + ln15;
                if (e < E_) op[e] = o[rf][n][tt] * inv;
            }
        }
    }
}

extern "C" void kernel_launch(void* const* d_in, const int* in_sizes, int n_in,
                              void* d_out, int out_size, void* d_ws, size_t ws_size,
                              hipStream_t stream) {
    const float* x  = (const float*)d_in[0];
    const float* Wq = (const float*)d_in[1];
    const float* Wk = (const float*)d_in[2];
    const float* Wv = (const float*)d_in[3];
    float* out = (float*)d_out;

    unsigned short* xb    = (unsigned short*)d_ws;                 // [M_][KP]
    unsigned short* wt    = xb + (size_t)M_ * KP;                  // [3][EP][KP]
    unsigned short* qbuf  = wt + (size_t)3 * EP * KP;              // [M_][EP]
    unsigned short* kbuf  = qbuf + (size_t)M_ * EP;                // [M_][KSP]
    unsigned short* vtbuf = kbuf + (size_t)M_ * KSP;               // [B_][EP][S_]

    prep_x<<<dim3(M_ * (KP / 8) / 256), 256, 0, stream>>>(x, xb);
    prep_w<<<dim3(3 * EP * KP / 256), 256, 0, stream>>>(Wq, Wk, Wv, wt);
    gemm_qkv<<<dim3(256, 3), 256, 0, stream>>>(xb, wt, qbuf, kbuf, vtbuf);
    attn_kernel<<<dim3(512), 256, 0, stream>>>(qbuf, kbuf, vtbuf, out);
}

// Round 22
// 171.908 us; speedup vs baseline: 1.7153x; 1.0999x over previous
//
#include <hip/hip_runtime.h>
#include <hip/hip_bf16.h>

#define B_  16
#define S_  2048
#define F_  800
#define E_  200
#define EP  224          // padded E (multiple of 32)
#define KP  832          // padded K (26 * 32)
#define KSP 256          // kbuf row pitch in shorts (32 x 16B slots, pow2 for swizzle)
#define M_  (B_ * S_)    // 32768

typedef __attribute__((ext_vector_type(8))) short short8;
typedef __attribute__((ext_vector_type(4))) float f32x4;

// scale = 1/sqrt(960); folded with log2(e) into Q so softmax runs in exp2 domain
#define QSCL (0.03227486121839514f * 1.4426950408889634f)

__device__ __forceinline__ unsigned short f2bf(float f) {
    __hip_bfloat16 h = __float2bfloat16(f);
    return *reinterpret_cast<unsigned short*>(&h);
}

__device__ __forceinline__ float exp2_fast(float x) {
    float r;
    asm("v_exp_f32 %0, %1" : "=v"(r) : "v"(x));
    return r;
}

__device__ __forceinline__ float rcp_fast(float x) {
    float r;
    asm("v_rcp_f32 %0, %1" : "=v"(r) : "v"(x));
    return r;
}

// tanh-form GELU (max |err| vs exact ~5e-4, below bf16 noise here)
__device__ __forceinline__ float gelu_fast(float x) {
    const float i = x + 0.044715f * x * x * x;
    const float z = 2.302265314f * i;              // 2*0.79788456*log2(e) * i
    return x * rcp_fast(1.0f + exp2_fast(-z));
}

__device__ __forceinline__ void gload_lds16(const void* g, void* l) {
    __builtin_amdgcn_global_load_lds(
        (const __attribute__((address_space(1))) unsigned int*)g,
        (__attribute__((address_space(3))) unsigned int*)l, 16, 0, 0);
}

// ---------------- prep: X fp32 -> bf16 padded [M][KP] ----------------
__global__ __launch_bounds__(256)
void prep_x(const float* __restrict__ x, unsigned short* __restrict__ xb) {
    const int id = blockIdx.x * 256 + threadIdx.x;
    const int r  = id / (KP / 8);
    const int c8 = id % (KP / 8);
    ushort4 lo = {0, 0, 0, 0}, hi = {0, 0, 0, 0};
    if (c8 < F_ / 8) {
        const float4 a = *reinterpret_cast<const float4*>(x + (size_t)r * F_ + c8 * 8);
        const float4 b = *reinterpret_cast<const float4*>(x + (size_t)r * F_ + c8 * 8 + 4);
        lo.x = f2bf(a.x); lo.y = f2bf(a.y); lo.z = f2bf(a.z); lo.w = f2bf(a.w);
        hi.x = f2bf(b.x); hi.y = f2bf(b.y); hi.z = f2bf(b.z); hi.w = f2bf(b.w);
    }
    unsigned short* dst = xb + (size_t)r * KP + c8 * 8;
    *reinterpret_cast<ushort4*>(dst) = lo;
    *reinterpret_cast<ushort4*>(dst + 4) = hi;
}

// ---------------- prep: W^T bf16 padded wt[3][EP][KP] ----------------
__global__ __launch_bounds__(256)
void prep_w(const float* __restrict__ Wq, const float* __restrict__ Wk,
            const float* __restrict__ Wv, unsigned short* __restrict__ wt) {
    const int id = blockIdx.x * 256 + threadIdx.x;
    const int sel = id / (EP * KP);
    const int rem = id % (EP * KP);
    const int e = rem / KP;
    const int k = rem % KP;
    const float* W = (sel == 0) ? Wq : ((sel == 1) ? Wk : Wv);
    float v = (e < E_ && k < F_) ? W[(size_t)k * E_ + e] : 0.0f;
    wt[id] = f2bf(v);
}

// ---------------- Stage 1 GEMM: Q/K/V = gelu(Xb @ W) ----------------
// (unchanged from the round-13/15 passing source)
#define STAGE(XB, WB, KK) do {                                                   \
    const int k0s = (KK) * 32;                                                   \
    _Pragma("unroll")                                                            \
    for (int i = 0; i < 2; ++i) {                                                \
        const int j = w * 2 + i;                                                 \
        const int row = 16 * j + rS;                                             \
        gload_lds16(xb + (size_t)(m0 + row) * KP + k0s + ((pS ^ (row & 3)) * 8), \
                    &XB[j * 512]);                                               \
    }                                                                            \
    _Pragma("unroll")                                                            \
    for (int i = 0; i < 4; ++i) {                                                \
        const int j = i * 4 + w;                                                 \
        if (j < 14) {                                                            \
            const int row = 16 * j + rS;                                         \
            gload_lds16(wsel + (size_t)row * KP + k0s + ((pS ^ (row & 3)) * 8),  \
                        &WB[j * 512]);                                           \
        }                                                                        \
    }                                                                            \
} while (0)

#define COMPUTE(XB, WB) do {                                                     \
    short8 afr[4];                                                               \
    _Pragma("unroll")                                                            \
    for (int rf = 0; rf < 4; ++rf) {                                             \
        const int row = wr * 64 + rf * 16 + ln15;                                \
        afr[rf] = *reinterpret_cast<const short8*>(                              \
            &XB[row * 32 + ((g ^ (row & 3)) * 8)]);                              \
    }                                                                            \
    _Pragma("unroll")                                                            \
    for (int cf = 0; cf < 7; ++cf) {                                             \
        const int row = wc * 112 + cf * 16 + ln15;                               \
        short8 bfr = *reinterpret_cast<const short8*>(                           \
            &WB[row * 32 + ((g ^ (row & 3)) * 8)]);                              \
        _Pragma("unroll")                                                        \
        for (int rf = 0; rf < 4; ++rf)                                           \
            acc[rf][cf] = __builtin_amdgcn_mfma_f32_16x16x32_bf16(               \
                afr[rf], bfr, acc[rf][cf], 0, 0, 0);                             \
    }                                                                            \
} while (0)

__global__ __launch_bounds__(256, 2)
void gemm_qkv(const unsigned short* __restrict__ xb,
              const unsigned short* __restrict__ wt,
              unsigned short* __restrict__ qbuf,
              unsigned short* __restrict__ kbuf,
              unsigned short* __restrict__ vtbuf) {
    const int sel = blockIdx.y;
    const int m0 = blockIdx.x * 128;
    const int t = threadIdx.x;
    const int lane = t & 63;
    const int w = t >> 6;
    const int wr = w >> 1;
    const int wc = w & 1;
    const int ln15 = lane & 15;
    const int g = lane >> 4;

    __shared__ __align__(16) unsigned short X0s[128 * 32];
    __shared__ __align__(16) unsigned short W0s[224 * 32];
    __shared__ __align__(16) unsigned short X1s[128 * 32];
    __shared__ __align__(16) unsigned short W1s[224 * 32];

    const unsigned short* wsel = wt + (size_t)sel * EP * KP;

    f32x4 acc[4][7];
#pragma unroll
    for (int i = 0; i < 4; ++i)
#pragma unroll
        for (int j = 0; j < 7; ++j) acc[i][j] = (f32x4)0.0f;

    const int rS = lane >> 2;            // staging row within 16-row chunk
    const int pS = lane & 3;             // staging physical granule

    STAGE(X0s, W0s, 0);
    __syncthreads();
#pragma unroll
    for (int p = 0; p < 12; ++p) {
        STAGE(X1s, W1s, 2 * p + 1);
        COMPUTE(X0s, W0s);
        __syncthreads();
        STAGE(X0s, W0s, 2 * p + 2);
        COMPUTE(X1s, W1s);
        __syncthreads();
    }
    STAGE(X1s, W1s, 25);
    COMPUTE(X0s, W0s);                   // kk = 24
    __syncthreads();
    COMPUTE(X1s, W1s);                   // kk = 25

    // epilogue: gelu + store; V padding col 200 <- 1.0 (ones-column: PV
    // MFMA computes softmax denominators for free in attn)
#pragma unroll
    for (int rf = 0; rf < 4; ++rf) {
        const int row = m0 + wr * 64 + rf * 16 + g * 4;
#pragma unroll
        for (int cf = 0; cf < 7; ++cf) {
            const int col = wc * 112 + cf * 16 + ln15;
            if (sel == 0) {
#pragma unroll
                for (int tt = 0; tt < 4; ++tt)
                    qbuf[(size_t)(row + tt) * EP + col] =
                        f2bf(gelu_fast(acc[rf][cf][tt]) * QSCL);
            } else if (sel == 1) {
#pragma unroll
                for (int tt = 0; tt < 4; ++tt)
                    kbuf[(size_t)(row + tt) * KSP + col] = f2bf(gelu_fast(acc[rf][cf][tt]));
            } else {
                const int bb = row >> 11, s = row & 2047;
                ushort4 pk;
                if (col == 200) {
                    pk.x = 0x3F80; pk.y = 0x3F80; pk.z = 0x3F80; pk.w = 0x3F80;
                } else {
                    pk.x = f2bf(gelu_fast(acc[rf][cf][0]));
                    pk.y = f2bf(gelu_fast(acc[rf][cf][1]));
                    pk.z = f2bf(gelu_fast(acc[rf][cf][2]));
                    pk.w = f2bf(gelu_fast(acc[rf][cf][3]));
                }
                *reinterpret_cast<ushort4*>(
                    &vtbuf[((size_t)(bb * EP + col)) * S_ + s]) = pk;
            }
        }
    }
}

// ---------------- Stage 2: flash attention (R15 + proven deltas) ----------
// BQ=128, 8 waves x 16 q-rows (512 thr), BKV=64 double-buffered — the R15
// 98us config verbatim, plus: (1) full-spread K swizzle phys = p^((row*4)&31)
// (correctness-proven in R17's passing run; pure layout permutation);
// (2) s_setprio(1) around MFMA clusters (T5, scheduling-only).
#define BQ  128
#define BKV 64

#define ASTAGE(KB, VB, KT) do {                                                  \
    const int kv0s = (KT) * BKV;                                                 \
    {   /* K: 32 x 1KB calls, 4 per wave, 2 rows each */                         \
        const int r_in = lane >> 5;                                              \
        const int p = lane & 31;                                                 \
        _Pragma("unroll")                                                        \
        for (int i = 0; i < 4; ++i) {                                            \
            const int j = w * 4 + i;                                             \
            const int row = 2 * j + r_in;                                        \
            gload_lds16(kb_b + (size_t)(kv0s + row) * KSP + ((p ^ ((row << 2) & 31)) * 8),\
                        &KB[j * 512]);                                           \
        }                                                                        \
    }                                                                            \
    {   /* V: 28 x 1KB calls, 8 rows each */                                     \
        const int r_in = lane >> 3;                                              \
        const int p = lane & 7;                                                  \
        _Pragma("unroll")                                                        \
        for (int i = 0; i < 4; ++i) {                                            \
            const int j = i * 8 + w;                                             \
            if (j < 28) {                                                        \
                const int row = 8 * j + r_in;                                    \
                gload_lds16(vt_b + (size_t)row * S_ + kv0s + ((p ^ (row & 7)) * 8),\
                            &VB[j * 512]);                                       \
            }                                                                    \
        }                                                                        \
    }                                                                            \
} while (0)

#define ACOMPUTE(KB, VB) do {                                                    \
    f32x4 sacc[4];                                                               \
    __builtin_amdgcn_s_setprio(1);                                               \
    _Pragma("unroll")                                                            \
    for (int n = 0; n < 4; ++n) {                                                \
        f32x4 a = (f32x4)0.0f;                                                   \
        const int krow = n * 16 + ln15;                                          \
        const unsigned short* kr = &KB[krow * KSP];                              \
        const int rx = (krow << 2) & 31;                                         \
        _Pragma("unroll")                                                        \
        for (int s = 0; s < 7; ++s) {                                            \
            short8 bf = *reinterpret_cast<const short8*>(                        \
                kr + (((s * 4 + g) ^ rx) * 8));                                  \
            a = __builtin_amdgcn_mfma_f32_16x16x32_bf16(qf[s], bf, a, 0, 0, 0);  \
        }                                                                        \
        sacc[n] = a;                                                             \
    }                                                                            \
    __builtin_amdgcn_s_setprio(0);                                               \
    _Pragma("unroll")                                                            \
    for (int n = 0; n < 4; ++n)                                                  \
        _Pragma("unroll")                                                        \
        for (int tt = 0; tt < 4; ++tt)                                           \
            Plds[w][g * 4 + tt][n * 16 + ln15] = f2bf(exp2_fast(sacc[n][tt]));   \
    short8 pf0 = *reinterpret_cast<const short8*>(&Plds[w][ln15][g * 8]);        \
    short8 pf1 = *reinterpret_cast<const short8*>(&Plds[w][ln15][32 + g * 8]);   \
    __builtin_amdgcn_s_setprio(1);                                               \
    _Pragma("unroll")                                                            \
    for (int n = 0; n < 14; ++n) {                                               \
        const int vrow = n * 16 + ln15;                                          \
        const unsigned short* vr = &VB[vrow * 64];                               \
        const int rx = vrow & 7;                                                 \
        short8 b0 = *reinterpret_cast<const short8*>(vr + ((g ^ rx) * 8));       \
        short8 b1 = *reinterpret_cast<const short8*>(vr + (((4 + g) ^ rx) * 8)); \
        o[n] = __builtin_amdgcn_mfma_f32_16x16x32_bf16(pf0, b0, o[n], 0, 0, 0);  \
        o[n] = __builtin_amdgcn_mfma_f32_16x16x32_bf16(pf1, b1, o[n], 0, 0, 0);  \
    }                                                                            \
    __builtin_amdgcn_s_setprio(0);                                               \
} while (0)

__global__ __launch_bounds__(512, 2)
void attn_kernel(const unsigned short* __restrict__ qbuf,
                 const unsigned short* __restrict__ kbuf,
                 const unsigned short* __restrict__ vtbuf,
                 float* __restrict__ out) {
    // XCD-aware role remap: XCD c serves batches {2c, 2c+1} (K/V 1.8MB < 4MB L2)
    const int id = blockIdx.x;            // 0..255
    const int slot = id >> 3;             // 0..31
    const int b = 2 * (id & 7) + (slot >> 4);
    const int q0 = (slot & 15) * BQ;
    const int t = threadIdx.x;
    const int lane = t & 63;
    const int w = t >> 6;                 // 0..7
    const int ln15 = lane & 15;
    const int g = lane >> 4;              // 0..3

    __shared__ __align__(16) unsigned short Ks[2][BKV * KSP];   // 2 x 32KB
    __shared__ __align__(16) unsigned short Vts[2][EP * 64];    // 2 x 28KB
    __shared__ __align__(16) unsigned short Plds[8][16][68];    // 17KB

    // Q fragments: 16 rows per wave (pre-scaled by scale*log2e)
    short8 qf[7];
    {
        const unsigned short* qp =
            qbuf + (size_t)(b * S_ + q0 + w * 16 + ln15) * EP + g * 8;
#pragma unroll
        for (int s = 0; s < 7; ++s)
            qf[s] = *reinterpret_cast<const short8*>(qp + s * 32);
    }

    f32x4 o[14];
#pragma unroll
    for (int i = 0; i < 14; ++i) o[i] = (f32x4)0.0f;

    const unsigned short* kb_b = kbuf + (size_t)b * S_ * KSP;
    const unsigned short* vt_b = vtbuf + (size_t)b * EP * S_;

    ASTAGE(Ks[0], Vts[0], 0);
    __syncthreads();
    for (int kt = 0; kt < S_ / BKV - 1; ++kt) {
        const int cur = kt & 1;
        ASTAGE(Ks[cur ^ 1], Vts[cur ^ 1], kt + 1);
        ACOMPUTE(Ks[cur], Vts[cur]);
        __syncthreads();
    }
    ACOMPUTE(Ks[1], Vts[1]);              // tile 31 (odd -> buffer 1)

    // epilogue: l = o[12] at col 200 (ln15==8); broadcast, normalize, store
    {
        float l[4];
#pragma unroll
        for (int tt = 0; tt < 4; ++tt)
            l[tt] = __shfl(o[12][tt], (lane & 48) + 8, 64);
#pragma unroll
        for (int tt = 0; tt < 4; ++tt) {
            const float inv = 1.0f / l[tt];
            const int row = q0 + w * 16 + g * 4 + tt;
            float* op = out + (size_t)(b * S_ + row) * E_;
#pragma unroll
            for (int n = 0; n < 13; ++n) {
                const int e = n * 16 + ln15;
                if (e < E_) op[e] = o[n][tt] * inv;
            }
        }
    }
}

extern "C" void kernel_launch(void* const* d_in, const int* in_sizes, int n_in,
                              void* d_out, int out_size, void* d_ws, size_t ws_size,
                              hipStream_t stream) {
    const float* x  = (const float*)d_in[0];
    const float* Wq = (const float*)d_in[1];
    const float* Wk = (const float*)d_in[2];
    const float* Wv = (const float*)d_in[3];
    float* out = (float*)d_out;

    unsigned short* xb    = (unsigned short*)d_ws;                 // [M_][KP]
    unsigned short* wt    = xb + (size_t)M_ * KP;                  // [3][EP][KP]
    unsigned short* qbuf  = wt + (size_t)3 * EP * KP;              // [M_][EP]
    unsigned short* kbuf  = qbuf + (size_t)M_ * EP;                // [M_][KSP]
    unsigned short* vtbuf = kbuf + (size_t)M_ * KSP;               // [B_][EP][S_]

    prep_x<<<dim3(M_ * (KP / 8) / 256), 256, 0, stream>>>(x, xb);
    prep_w<<<dim3(3 * EP * KP / 256), 256, 0, stream>>>(Wq, Wk, Wv, wt);
    gemm_qkv<<<dim3(256, 3), 256, 0, stream>>>(xb, wt, qbuf, kbuf, vtbuf);
    attn_kernel<<<dim3(256), 512, 0, stream>>>(qbuf, kbuf, vtbuf, out);
}